// Round 2
// baseline (503.803 us; speedup 1.0000x reference)
//
#include <hip/hip_runtime.h>
#include <hip/hip_bf16.h>

#define IN_CH 48
#define OUT_CH 48
#define BN_EPS 1e-5f

__device__ __forceinline__ float bf2f(ushort u) {
    union { unsigned int i; float f; } v;
    v.i = ((unsigned int)u) << 16;
    return v.f;
}
__device__ __forceinline__ ushort f2bf(float f) {
    __hip_bfloat16 h = __float2bfloat16(f);  // round-to-nearest-even
    return *(ushort*)&h;
}

// ---------------------------------------------------------------------------
// k_count: counts[dst[e]] += 1 (int atomics; self-loop added later as +1)
// ---------------------------------------------------------------------------
__global__ void k_count(const int* __restrict__ dst, int* __restrict__ counts, int E) {
    int e = blockIdx.x * blockDim.x + threadIdx.x;
    if (e < E) atomicAdd(&counts[dst[e]], 1);
}

// ---------------------------------------------------------------------------
// k_scan: exclusive prefix sum of counts -> row_end (holds START; k_fill's
// atomicAdd turns it into END). Also dinv[i] = rsqrt(counts[i]+1).
// Single block, 1024 threads, two-pass chunk scan.
// ---------------------------------------------------------------------------
__global__ __launch_bounds__(1024) void k_scan(const int* __restrict__ counts,
                                               int* __restrict__ row_end,
                                               float* __restrict__ dinv, int N) {
    __shared__ int lds[1024];
    int tid = threadIdx.x;
    int C = (N + 1023) >> 10;
    int lo = tid * C, hi = min(lo + C, N);
    int sum = 0;
    for (int i = lo; i < hi; ++i) sum += counts[i];
    lds[tid] = sum;
    __syncthreads();
    // Hillis-Steele inclusive scan
    for (int off = 1; off < 1024; off <<= 1) {
        int v = (tid >= off) ? lds[tid - off] : 0;
        __syncthreads();
        lds[tid] += v;
        __syncthreads();
    }
    int run = (tid == 0) ? 0 : lds[tid - 1];
    for (int i = lo; i < hi; ++i) {
        int c = counts[i];
        row_end[i] = run;                      // start position
        dinv[i] = rsqrtf((float)c + 1.0f);     // deg includes self loop
        run += c;
    }
}

// ---------------------------------------------------------------------------
// k_gemm: g[i] = bf16( (x[i] @ W) * dinv[i] )   [pre-scaled by src dinv]
// ---------------------------------------------------------------------------
__global__ __launch_bounds__(256) void k_gemm(const float* __restrict__ x,
                                              const float* __restrict__ W,
                                              const float* __restrict__ dinv,
                                              ushort* __restrict__ g, int N) {
    __shared__ float Wl[IN_CH * OUT_CH];
    for (int idx = threadIdx.x; idx < IN_CH * OUT_CH / 4; idx += blockDim.x)
        ((float4*)Wl)[idx] = ((const float4*)W)[idx];
    __syncthreads();

    int i = blockIdx.x * blockDim.x + threadIdx.x;
    if (i >= N) return;

    float xr[IN_CH];
    const float4* xp = (const float4*)(x + (size_t)i * IN_CH);
#pragma unroll
    for (int k = 0; k < IN_CH / 4; ++k) {
        float4 v = xp[k];
        xr[4 * k] = v.x; xr[4 * k + 1] = v.y; xr[4 * k + 2] = v.z; xr[4 * k + 3] = v.w;
    }
    float di = dinv[i];

    ushort row[OUT_CH];
#pragma unroll
    for (int c4 = 0; c4 < OUT_CH / 4; ++c4) {
        float4 acc = make_float4(0.f, 0.f, 0.f, 0.f);
#pragma unroll
        for (int k = 0; k < IN_CH; ++k) {
            float4 w = ((const float4*)Wl)[k * (OUT_CH / 4) + c4];
            acc.x += xr[k] * w.x; acc.y += xr[k] * w.y;
            acc.z += xr[k] * w.z; acc.w += xr[k] * w.w;
        }
        row[4 * c4 + 0] = f2bf(acc.x * di);
        row[4 * c4 + 1] = f2bf(acc.y * di);
        row[4 * c4 + 2] = f2bf(acc.z * di);
        row[4 * c4 + 3] = f2bf(acc.w * di);
    }
    uint4* gp = (uint4*)(g + (size_t)i * OUT_CH);  // 96B row, 16B aligned
#pragma unroll
    for (int j = 0; j < 6; ++j) gp[j] = ((uint4*)row)[j];
}

// ---------------------------------------------------------------------------
// k_fill: bucket edges by dst. pos = old cursor; row_end becomes END after.
// ---------------------------------------------------------------------------
__global__ void k_fill(const int* __restrict__ src, const int* __restrict__ dst,
                       int* __restrict__ row_end, int* __restrict__ sorted_src, int E) {
    int e = blockIdx.x * blockDim.x + threadIdx.x;
    if (e < E) {
        int pos = atomicAdd(&row_end[dst[e]], 1);
        sorted_src[pos] = src[e];
    }
}

// ---------------------------------------------------------------------------
// k_gather: one thread per (node, channel).
// out[d][c] = dinv[d] * ( g[d][c] + sum_{s in in(d)} g[s][c] )
// ---------------------------------------------------------------------------
__global__ __launch_bounds__(256) void k_gather(const int* __restrict__ sorted_src,
                                                const int* __restrict__ row_end,
                                                const int* __restrict__ counts,
                                                const ushort* __restrict__ g,
                                                const float* __restrict__ dinv,
                                                float* __restrict__ out, int N) {
    int t = blockIdx.x * blockDim.x + threadIdx.x;
    if (t >= N * OUT_CH) return;
    int node = t / OUT_CH;
    int c = t - node * OUT_CH;
    int end = row_end[node];
    int cnt = counts[node];
    int e = end - cnt;
    float acc = bf2f(g[(size_t)node * OUT_CH + c]);  // self loop
    for (; e + 4 <= end; e += 4) {
        int s0 = sorted_src[e];
        int s1 = sorted_src[e + 1];
        int s2 = sorted_src[e + 2];
        int s3 = sorted_src[e + 3];
        float a0 = bf2f(g[(size_t)s0 * OUT_CH + c]);
        float a1 = bf2f(g[(size_t)s1 * OUT_CH + c]);
        float a2 = bf2f(g[(size_t)s2 * OUT_CH + c]);
        float a3 = bf2f(g[(size_t)s3 * OUT_CH + c]);
        acc += (a0 + a1) + (a2 + a3);
    }
    for (; e < end; ++e) acc += bf2f(g[(size_t)sorted_src[e] * OUT_CH + c]);
    out[t] = acc * dinv[node];
}

// ---------------------------------------------------------------------------
// k_stats: per-channel sum and sum-of-squares of out
// ---------------------------------------------------------------------------
__global__ __launch_bounds__(768) void k_stats(const float* __restrict__ v,
                                               float* __restrict__ stats, int N) {
    __shared__ float ls[16][OUT_CH];
    __shared__ float ls2[16][OUT_CH];
    int c = threadIdx.x;   // 0..47
    int ty = threadIdx.y;  // 0..15
    float s = 0.f, s2 = 0.f;
    for (int r = blockIdx.x * 16 + ty; r < N; r += gridDim.x * 16) {
        float u = v[(size_t)r * OUT_CH + c];
        s += u;
        s2 += u * u;
    }
    ls[ty][c] = s;
    ls2[ty][c] = s2;
    __syncthreads();
    for (int h = 8; h > 0; h >>= 1) {
        if (ty < h) {
            ls[ty][c] += ls[ty + h][c];
            ls2[ty][c] += ls2[ty + h][c];
        }
        __syncthreads();
    }
    if (ty == 0) {
        atomicAdd(&stats[c], ls[0][c]);
        atomicAdd(&stats[OUT_CH + c], ls2[0][c]);
    }
}

// ---------------------------------------------------------------------------
// k_final: BN (batch stats) + ReLU, in place. GCN bias b cancels under BN.
// ---------------------------------------------------------------------------
__global__ void k_final(float* __restrict__ out, const float* __restrict__ stats,
                        const float* __restrict__ gamma,
                        const float* __restrict__ beta, int N) {
    int t = blockIdx.x * blockDim.x + threadIdx.x;
    int total = N * OUT_CH;
    if (t >= total) return;
    int c = t % OUT_CH;
    float invN = 1.0f / (float)N;
    float m = stats[c] * invN;
    float var = stats[OUT_CH + c] * invN - m * m;
    float y = (out[t] - m) * rsqrtf(var + BN_EPS) * gamma[c] + beta[c];
    out[t] = fmaxf(y, 0.0f);
}

extern "C" void kernel_launch(void* const* d_in, const int* in_sizes, int n_in,
                              void* d_out, int out_size, void* d_ws, size_t ws_size,
                              hipStream_t stream) {
    const float* x     = (const float*)d_in[0];
    const int*   ei    = (const int*)d_in[1];
    const float* W     = (const float*)d_in[2];
    // d_in[3] = b : constant per-channel offset cancels in BatchNorm -> unused
    const float* gamma = (const float*)d_in[4];
    const float* beta  = (const float*)d_in[5];
    float*       out   = (float*)d_out;

    int N = in_sizes[0] / IN_CH;
    int E = in_sizes[1] / 2;
    const int* src = ei;       // edge_index[0]
    const int* dst = ei + E;   // edge_index[1]

    // workspace layout (bytes):
    // [0, 4N)              counts (int)
    // [4N, 4N+512)         stats  (float[128], only 96 used)
    // [4N+512, 8N+512)     row_end (int)
    // [8N+512, 12N+512)    dinv (float)
    // [12N+512, 12N+512+4E)   sorted_src (int)
    // [.., +96N)           g (bf16[N*48]) -- 16B aligned (offset 7600512 for N=100K)
    char* wsb = (char*)d_ws;
    int*    counts     = (int*)wsb;
    float*  stats      = (float*)(wsb + (size_t)4 * N);
    int*    row_end    = (int*)(wsb + (size_t)4 * N + 512);
    float*  dinv       = (float*)(wsb + (size_t)8 * N + 512);
    int*    sorted_src = (int*)(wsb + (size_t)12 * N + 512);
    ushort* g          = (ushort*)(wsb + (size_t)12 * N + 512 + (size_t)4 * E);

    int b = 256;

    // 1. zero counts + stats
    hipMemsetAsync(d_ws, 0, (size_t)4 * N + 512, stream);
    // 2. in-degree counts (excl. self loop)
    k_count<<<(E + b - 1) / b, b, 0, stream>>>(dst, counts, E);
    // 3. exclusive scan -> row starts; dinv
    k_scan<<<1, 1024, 0, stream>>>(counts, row_end, dinv, N);
    // 4. g = bf16((x@W) * dinv)
    k_gemm<<<(N + b - 1) / b, b, 0, stream>>>(x, W, dinv, g, N);
    // 5. bucket-sort src ids by dst
    k_fill<<<(E + b - 1) / b, b, 0, stream>>>(src, dst, row_end, sorted_src, E);
    // 6. gather + self loop + dst dinv
    int totalT = N * OUT_CH;
    k_gather<<<(totalT + b - 1) / b, b, 0, stream>>>(sorted_src, row_end, counts, g, dinv, out, N);
    // 7. BN stats
    dim3 sblk(OUT_CH, 16);
    k_stats<<<256, sblk, 0, stream>>>(out, stats, N);
    // 8. BN + ReLU in place
    k_final<<<(totalT + b - 1) / b, b, 0, stream>>>(out, stats, gamma, beta, N);
}

// Round 3
// 292.651 us; speedup vs baseline: 1.7215x; 1.7215x over previous
//
#include <hip/hip_runtime.h>
#include <hip/hip_bf16.h>

#define IN_CH 48
#define OUT_CH 48
#define BN_EPS 1e-5f
#define SCAN_CHUNK 1024   // elements per block in the scan kernels

__device__ __forceinline__ float bf2f(ushort u) {
    union { unsigned int i; float f; } v;
    v.i = ((unsigned int)u) << 16;
    return v.f;
}
__device__ __forceinline__ ushort f2bf(float f) {
    __hip_bfloat16 h = __float2bfloat16(f);  // round-to-nearest-even
    return *(ushort*)&h;
}

// ---------------------------------------------------------------------------
// k_count: counts[dst[e]] += 1 (int atomics; self-loop added later as +1)
// ---------------------------------------------------------------------------
__global__ void k_count(const int* __restrict__ dst, int* __restrict__ counts, int E) {
    int e = blockIdx.x * blockDim.x + threadIdx.x;
    if (e < E) atomicAdd(&counts[dst[e]], 1);
}

// ---------------------------------------------------------------------------
// Scan stage A: per-block sum of counts chunks (1024 elems / block, 256 thr)
// ---------------------------------------------------------------------------
__global__ __launch_bounds__(256) void k_blocksum(const int* __restrict__ counts,
                                                  int* __restrict__ bsum, int N) {
    __shared__ int lds[256];
    int b = blockIdx.x;
    int t = threadIdx.x;
    int base = b * SCAN_CHUNK + t * 4;
    int s = 0;
#pragma unroll
    for (int j = 0; j < 4; ++j) {
        int i = base + j;
        if (i < N) s += counts[i];
    }
    lds[t] = s;
    __syncthreads();
    for (int h = 128; h > 0; h >>= 1) {
        if (t < h) lds[t] += lds[t + h];
        __syncthreads();
    }
    if (t == 0) bsum[b] = lds[0];
}

// ---------------------------------------------------------------------------
// Scan stage B: single block scans nb (<=256) block sums -> exclusive boff
// ---------------------------------------------------------------------------
__global__ __launch_bounds__(256) void k_scanb(const int* __restrict__ bsum,
                                               int* __restrict__ boff, int nb) {
    __shared__ int lds[256];
    int t = threadIdx.x;
    int v = (t < nb) ? bsum[t] : 0;
    lds[t] = v;
    __syncthreads();
    for (int off = 1; off < 256; off <<= 1) {
        int u = (t >= off) ? lds[t - off] : 0;
        __syncthreads();
        lds[t] += u;
        __syncthreads();
    }
    if (t < nb) boff[t] = lds[t] - v;  // exclusive
}

// ---------------------------------------------------------------------------
// Scan stage C: per-block exclusive scan of counts + boff[b] -> row_end
// (holds START; k_fill's atomicAdd turns it into END). Also dinv.
// ---------------------------------------------------------------------------
__global__ __launch_bounds__(256) void k_rowstart(const int* __restrict__ counts,
                                                  const int* __restrict__ boff,
                                                  int* __restrict__ row_end,
                                                  float* __restrict__ dinv, int N) {
    __shared__ int lds[256];
    int b = blockIdx.x;
    int t = threadIdx.x;
    int base = b * SCAN_CHUNK + t * 4;
    int c[4];
    int s = 0;
#pragma unroll
    for (int j = 0; j < 4; ++j) {
        int i = base + j;
        c[j] = (i < N) ? counts[i] : 0;
        s += c[j];
    }
    lds[t] = s;
    __syncthreads();
    // inclusive Hillis-Steele over thread sums
    for (int off = 1; off < 256; off <<= 1) {
        int u = (t >= off) ? lds[t - off] : 0;
        __syncthreads();
        lds[t] += u;
        __syncthreads();
    }
    int run = boff[b] + lds[t] - s;  // exclusive offset for this thread
#pragma unroll
    for (int j = 0; j < 4; ++j) {
        int i = base + j;
        if (i < N) {
            row_end[i] = run;
            dinv[i] = rsqrtf((float)c[j] + 1.0f);  // deg includes self loop
            run += c[j];
        }
    }
}

// ---------------------------------------------------------------------------
// k_gemm: g[i] = bf16( (x[i] @ W) * dinv[i] )   [pre-scaled by src dinv]
// ---------------------------------------------------------------------------
__global__ __launch_bounds__(256) void k_gemm(const float* __restrict__ x,
                                              const float* __restrict__ W,
                                              const float* __restrict__ dinv,
                                              ushort* __restrict__ g, int N) {
    __shared__ float Wl[IN_CH * OUT_CH];
    for (int idx = threadIdx.x; idx < IN_CH * OUT_CH / 4; idx += blockDim.x)
        ((float4*)Wl)[idx] = ((const float4*)W)[idx];
    __syncthreads();

    int i = blockIdx.x * blockDim.x + threadIdx.x;
    if (i >= N) return;

    float xr[IN_CH];
    const float4* xp = (const float4*)(x + (size_t)i * IN_CH);
#pragma unroll
    for (int k = 0; k < IN_CH / 4; ++k) {
        float4 v = xp[k];
        xr[4 * k] = v.x; xr[4 * k + 1] = v.y; xr[4 * k + 2] = v.z; xr[4 * k + 3] = v.w;
    }
    float di = dinv[i];

    ushort row[OUT_CH];
#pragma unroll
    for (int c4 = 0; c4 < OUT_CH / 4; ++c4) {
        float4 acc = make_float4(0.f, 0.f, 0.f, 0.f);
#pragma unroll
        for (int k = 0; k < IN_CH; ++k) {
            float4 w = ((const float4*)Wl)[k * (OUT_CH / 4) + c4];
            acc.x += xr[k] * w.x; acc.y += xr[k] * w.y;
            acc.z += xr[k] * w.z; acc.w += xr[k] * w.w;
        }
        row[4 * c4 + 0] = f2bf(acc.x * di);
        row[4 * c4 + 1] = f2bf(acc.y * di);
        row[4 * c4 + 2] = f2bf(acc.z * di);
        row[4 * c4 + 3] = f2bf(acc.w * di);
    }
    uint4* gp = (uint4*)(g + (size_t)i * OUT_CH);  // 96B row, 16B aligned
#pragma unroll
    for (int j = 0; j < 6; ++j) gp[j] = ((uint4*)row)[j];
}

// ---------------------------------------------------------------------------
// k_fill: bucket edges by dst. pos = old cursor; row_end becomes END after.
// ---------------------------------------------------------------------------
__global__ void k_fill(const int* __restrict__ src, const int* __restrict__ dst,
                       int* __restrict__ row_end, int* __restrict__ sorted_src, int E) {
    int e = blockIdx.x * blockDim.x + threadIdx.x;
    if (e < E) {
        int pos = atomicAdd(&row_end[dst[e]], 1);
        sorted_src[pos] = src[e];
    }
}

// ---------------------------------------------------------------------------
// k_gather: one thread per (node, channel).
// out[d][c] = dinv[d] * ( g[d][c] + sum_{s in in(d)} g[s][c] )
// ---------------------------------------------------------------------------
__global__ __launch_bounds__(256) void k_gather(const int* __restrict__ sorted_src,
                                                const int* __restrict__ row_end,
                                                const int* __restrict__ counts,
                                                const ushort* __restrict__ g,
                                                const float* __restrict__ dinv,
                                                float* __restrict__ out, int N) {
    int t = blockIdx.x * blockDim.x + threadIdx.x;
    if (t >= N * OUT_CH) return;
    int node = t / OUT_CH;
    int c = t - node * OUT_CH;
    int end = row_end[node];
    int cnt = counts[node];
    int e = end - cnt;
    float acc = bf2f(g[(size_t)node * OUT_CH + c]);  // self loop
    for (; e + 4 <= end; e += 4) {
        int s0 = sorted_src[e];
        int s1 = sorted_src[e + 1];
        int s2 = sorted_src[e + 2];
        int s3 = sorted_src[e + 3];
        float a0 = bf2f(g[(size_t)s0 * OUT_CH + c]);
        float a1 = bf2f(g[(size_t)s1 * OUT_CH + c]);
        float a2 = bf2f(g[(size_t)s2 * OUT_CH + c]);
        float a3 = bf2f(g[(size_t)s3 * OUT_CH + c]);
        acc += (a0 + a1) + (a2 + a3);
    }
    for (; e < end; ++e) acc += bf2f(g[(size_t)sorted_src[e] * OUT_CH + c]);
    out[t] = acc * dinv[node];
}

// ---------------------------------------------------------------------------
// k_stats: per-channel sum and sum-of-squares of out
// ---------------------------------------------------------------------------
__global__ __launch_bounds__(768) void k_stats(const float* __restrict__ v,
                                               float* __restrict__ stats, int N) {
    __shared__ float ls[16][OUT_CH];
    __shared__ float ls2[16][OUT_CH];
    int c = threadIdx.x;   // 0..47
    int ty = threadIdx.y;  // 0..15
    float s = 0.f, s2 = 0.f;
    for (int r = blockIdx.x * 16 + ty; r < N; r += gridDim.x * 16) {
        float u = v[(size_t)r * OUT_CH + c];
        s += u;
        s2 += u * u;
    }
    ls[ty][c] = s;
    ls2[ty][c] = s2;
    __syncthreads();
    for (int h = 8; h > 0; h >>= 1) {
        if (ty < h) {
            ls[ty][c] += ls[ty + h][c];
            ls2[ty][c] += ls2[ty + h][c];
        }
        __syncthreads();
    }
    if (ty == 0) {
        atomicAdd(&stats[c], ls[0][c]);
        atomicAdd(&stats[OUT_CH + c], ls2[0][c]);
    }
}

// ---------------------------------------------------------------------------
// k_final: BN (batch stats) + ReLU, in place. GCN bias b cancels under BN.
// ---------------------------------------------------------------------------
__global__ void k_final(float* __restrict__ out, const float* __restrict__ stats,
                        const float* __restrict__ gamma,
                        const float* __restrict__ beta, int N) {
    int t = blockIdx.x * blockDim.x + threadIdx.x;
    int total = N * OUT_CH;
    if (t >= total) return;
    int c = t % OUT_CH;
    float invN = 1.0f / (float)N;
    float m = stats[c] * invN;
    float var = stats[OUT_CH + c] * invN - m * m;
    float y = (out[t] - m) * rsqrtf(var + BN_EPS) * gamma[c] + beta[c];
    out[t] = fmaxf(y, 0.0f);
}

extern "C" void kernel_launch(void* const* d_in, const int* in_sizes, int n_in,
                              void* d_out, int out_size, void* d_ws, size_t ws_size,
                              hipStream_t stream) {
    const float* x     = (const float*)d_in[0];
    const int*   ei    = (const int*)d_in[1];
    const float* W     = (const float*)d_in[2];
    // d_in[3] = b : constant per-channel offset cancels in BatchNorm -> unused
    const float* gamma = (const float*)d_in[4];
    const float* beta  = (const float*)d_in[5];
    float*       out   = (float*)d_out;

    int N = in_sizes[0] / IN_CH;
    int E = in_sizes[1] / 2;
    const int* src = ei;       // edge_index[0]
    const int* dst = ei + E;   // edge_index[1]

    int nb = (N + SCAN_CHUNK - 1) / SCAN_CHUNK;  // 98 for N=100K (must be <=256)

    // workspace layout (bytes):
    // [0, 4N)                 counts (int)
    // [4N, 4N+512)            stats  (float[128], only 96 used)
    // [4N+512, 8N+512)        row_end (int)
    // [8N+512, 12N+512)       dinv (float)
    // [12N+512, +4E)          sorted_src (int)
    // [.., +96N)              g (bf16[N*48]) -- 16B aligned
    // [.., +2048)             bsum (int[256]) + boff (int[256])
    char* wsb = (char*)d_ws;
    int*    counts     = (int*)wsb;
    float*  stats      = (float*)(wsb + (size_t)4 * N);
    int*    row_end    = (int*)(wsb + (size_t)4 * N + 512);
    float*  dinv       = (float*)(wsb + (size_t)8 * N + 512);
    int*    sorted_src = (int*)(wsb + (size_t)12 * N + 512);
    ushort* g          = (ushort*)(wsb + (size_t)12 * N + 512 + (size_t)4 * E);
    int*    bsum       = (int*)(wsb + (size_t)12 * N + 512 + (size_t)4 * E + (size_t)96 * N);
    int*    boff       = bsum + 256;

    int b = 256;

    // 1. zero counts + stats
    hipMemsetAsync(d_ws, 0, (size_t)4 * N + 512, stream);
    // 2. in-degree counts (excl. self loop)
    k_count<<<(E + b - 1) / b, b, 0, stream>>>(dst, counts, E);
    // 3. device-wide exclusive scan (3 small kernels) -> row starts; dinv
    k_blocksum<<<nb, 256, 0, stream>>>(counts, bsum, N);
    k_scanb<<<1, 256, 0, stream>>>(bsum, boff, nb);
    k_rowstart<<<nb, 256, 0, stream>>>(counts, boff, row_end, dinv, N);
    // 4. g = bf16((x@W) * dinv)
    k_gemm<<<(N + b - 1) / b, b, 0, stream>>>(x, W, dinv, g, N);
    // 5. bucket-sort src ids by dst
    k_fill<<<(E + b - 1) / b, b, 0, stream>>>(src, dst, row_end, sorted_src, E);
    // 6. gather + self loop + dst dinv
    int totalT = N * OUT_CH;
    k_gather<<<(totalT + b - 1) / b, b, 0, stream>>>(sorted_src, row_end, counts, g, dinv, out, N);
    // 7. BN stats
    dim3 sblk(OUT_CH, 16);
    k_stats<<<256, sblk, 0, stream>>>(out, stats, N);
    // 8. BN + ReLU in place
    k_final<<<(totalT + b - 1) / b, b, 0, stream>>>(out, stats, gamma, beta, N);
}